// Round 3
// 224.173 us; speedup vs baseline: 1.5057x; 1.5057x over previous
//
#include <hip/hip_runtime.h>
#include <math.h>

// Problem constants
#define HH 2048
#define EE 64
#define TOPK 8
#define NT 16384
#define MT 64            // tokens per WG (2 groups of 32)
#define KC 16            // K elems per chunk per K-quarter
#define KQR 512          // K range per K-quarter (in-WG K-split 4)
#define NCH 32           // KQR / KC
#define LS 68            // slog row stride (floats); 272 B, 16B-divisible

typedef __attribute__((ext_vector_type(8)))  short short8;  // 8 bf16 (4 VGPRs)
typedef __attribute__((ext_vector_type(16))) float f32x16;  // 32x32 MFMA acc

// 3-limb bf16 split: v = h + m + l + eps, |eps| <= 2^-25 |v|.
// h,m by truncation (residual exactly representable), l by RNE.
static __device__ __forceinline__ void cvt3(const float4& a, const float4& b,
                                            short8& h, short8& m, short8& l)
{
    const float v[8] = {a.x, a.y, a.z, a.w, b.x, b.y, b.z, b.w};
#pragma unroll
    for (int i = 0; i < 8; ++i) {
        const unsigned int u = __float_as_uint(v[i]);
        h[i] = (short)(u >> 16);
        const float r1 = v[i] - __uint_as_float(u & 0xffff0000u);
        const unsigned int u1 = __float_as_uint(r1);
        m[i] = (short)(u1 >> 16);
        const float r2 = r1 - __uint_as_float(u1 & 0xffff0000u);
        const unsigned int u2 = __float_as_uint(r2);
        l[i] = (short)((u2 + 0x7fffu + ((u2 >> 16) & 1u)) >> 16);
    }
}

// Swizzled 16B-unit index for limb p, expert e, k-octet bit cb (0/1) within a
// [3][64][16]-bf16 chunk block (384 units). XOR by (e>>2)&7 spreads the
// ds_read_b128 (fixed cb, 32 consecutive e) evenly over all 8 bank groups.
static __device__ __forceinline__ int swz_unit(int p, int e, int cb)
{
    const int v   = (p * 64 + e) * 2 + cb;
    const int low = (((e & 3) * 2 + cb) ^ ((e >> 2) & 7));
    return (v & ~7) | low;
}

// ---------------- Pre-kernel: W -> pre-swizzled 3-limb bf16 planes ----------
// ws layout: [c=0..31][kq=0..3][384 units][8 shorts]  (768 KB total)
__global__ __launch_bounds__(256) void wsplit(
    const float* __restrict__ w, short* __restrict__ wsw)
{
    const int e = blockIdx.x;        // expert 0..63
    const int o = threadIdx.x;       // k-octet 0..255
    const int k = o * 8;
    const float4 a = *(const float4*)(w + (size_t)e * HH + k);
    const float4 b = *(const float4*)(w + (size_t)e * HH + k + 4);
    short8 h, m, l;
    cvt3(a, b, h, m, l);

    const int kq = k >> 9;           // K-quarter
    const int c  = (k & 511) >> 4;   // chunk within quarter
    const int cb = (k >> 3) & 1;     // octet within chunk
    const size_t base = ((size_t)c * 4 + kq) * 384;
    *(short8*)(wsw + (base + swz_unit(0, e, cb)) * 8) = h;
    *(short8*)(wsw + (base + swz_unit(1, e, cb)) * 8) = m;
    *(short8*)(wsw + (base + swz_unit(2, e, cb)) * 8) = l;
}

// ---------------- Main kernel: fused router ----------------
// 512 threads = 8 waves: g = wv>>2 (32-token group), kq = wv&3 (K-quarter).
// x streamed once from HBM straight to registers; W limbs staged LDS-dbuf.
__global__ __launch_bounds__(512, 2) void router_fused(
    const float* __restrict__ x,          // [NT, H] fp32
    const short* __restrict__ wsw,        // pre-swizzled W limbs
    float* __restrict__ out_logits,
    float* __restrict__ out_wts,
    float* __restrict__ out_idx)
{
    __shared__ __align__(16) char smem_raw[49152];   // 48 KB
    short* ldsw = (short*)smem_raw;   // [2 buf][4 kq][384 units][8 shorts]
    float* slog = (float*)smem_raw;   // reused post-loop: [64][LS]

    const int t    = threadIdx.x;
    const int wv   = t >> 6;
    const int lane = t & 63;
    const int g    = wv >> 2;        // token group of 32
    const int kq   = wv & 3;         // K-quarter
    const int l5   = lane >> 5;      // k-octet within chunk
    const int lr   = lane & 31;      // token row (A) / expert col (B)
    const int tok0 = blockIdx.x * MT;

    // A source: 32B contiguous per lane; lanes l and l+32 cover one 64B line.
    const float* xp = x + (size_t)(tok0 + g * 32 + lr) * HH + kq * KQR + l5 * 8;

    f32x16 accM0 = {0}, accM1 = {0};   // hh terms (eb 0/1)
    f32x16 accS0 = {0}, accS1 = {0};   // small terms: hm+mh+hl+lh+mm

    // linear staging: block c (1536 units = 24 KB) -> buf; 3 units/thread
    auto stage = [&](int c, int buf) {
        const short* src = wsw + ((size_t)c * 1536 + t) * 8;
        short* dst = ldsw + ((size_t)buf * 1536 + t) * 8;
#pragma unroll
        for (int i = 0; i < 3; ++i)
            *(short8*)(dst + (size_t)i * 512 * 8) =
                *(const short8*)(src + (size_t)i * 512 * 8);
    };

    auto compute = [&](const float4& xa, const float4& xb, int buf) {
        short8 xh, xm, xl;
        cvt3(xa, xb, xh, xm, xl);
        const short* base = ldsw + ((size_t)buf * 1536 + kq * 384) * 8;
#pragma unroll
        for (int eb = 0; eb < 2; ++eb) {
            const int e = eb * 32 + lr;
            const short8 bh = *(const short8*)(base + swz_unit(0, e, l5) * 8);
            const short8 bm = *(const short8*)(base + swz_unit(1, e, l5) * 8);
            const short8 bl = *(const short8*)(base + swz_unit(2, e, l5) * 8);
            f32x16& AM = eb ? accM1 : accM0;
            f32x16& AS = eb ? accS1 : accS0;
            AM = __builtin_amdgcn_mfma_f32_32x32x16_bf16(xh, bh, AM, 0, 0, 0);
            AS = __builtin_amdgcn_mfma_f32_32x32x16_bf16(xh, bm, AS, 0, 0, 0);
            AS = __builtin_amdgcn_mfma_f32_32x32x16_bf16(xm, bh, AS, 0, 0, 0);
            AS = __builtin_amdgcn_mfma_f32_32x32x16_bf16(xh, bl, AS, 0, 0, 0);
            AS = __builtin_amdgcn_mfma_f32_32x32x16_bf16(xl, bh, AS, 0, 0, 0);
            AS = __builtin_amdgcn_mfma_f32_32x32x16_bf16(xm, bm, AS, 0, 0, 0);
        }
    };

    // prologue: stage chunk 0; prefetch x for chunks 0 and 1
    stage(0, 0);
    float4 xa0 = *(const float4*)(xp);
    float4 xa1 = *(const float4*)(xp + 4);
    float4 xb0 = *(const float4*)(xp + KC);
    float4 xb1 = *(const float4*)(xp + KC + 4);
    __syncthreads();

#pragma unroll 1
    for (int c = 0; c < NCH; c += 2) {
        stage(c + 1, 1);                       // c+1 <= 31 always
        compute(xa0, xa1, 0);
        if (c + 2 < NCH) {
            xa0 = *(const float4*)(xp + (c + 2) * KC);
            xa1 = *(const float4*)(xp + (c + 2) * KC + 4);
        }
        __syncthreads();

        if (c + 2 < NCH) stage(c + 2, 0);
        compute(xb0, xb1, 1);
        if (c + 3 < NCH) {
            xb0 = *(const float4*)(xp + (c + 3) * KC);
            xb1 = *(const float4*)(xp + (c + 3) * KC + 4);
        }
        __syncthreads();
    }

    // ---- K-quarter reduction into slog (smem reused; main loop done) ----
    // 32x32 C/D layout (m74/m101): col = lane&31, row = (r&3)+8*(r>>2)+4*(l>>5)
#pragma unroll 1
    for (int q = 0; q < 4; ++q) {
        if (kq == q) {
#pragma unroll
            for (int eb = 0; eb < 2; ++eb) {
                const f32x16& AM = eb ? accM1 : accM0;
                const f32x16& AS = eb ? accS1 : accS0;
                const int col = eb * 32 + lr;
#pragma unroll
                for (int r = 0; r < 16; ++r) {
                    const int row = g * 32 + (r & 3) + 8 * (r >> 2) + 4 * l5;
                    const float val = AM[r] + AS[r];
                    if (q == 0) slog[row * LS + col] = val;
                    else        slog[row * LS + col] += val;
                }
            }
        }
        __syncthreads();
    }

    // ---- coalesced logits write: 64 tokens x 64 experts ----
    {
        const int row = t >> 3;
        const int c8  = (t & 7) * 8;
        const float4 o0 = *(const float4*)&slog[row * LS + c8];
        const float4 o1 = *(const float4*)&slog[row * LS + c8 + 4];
        float* dst = out_logits + (size_t)(tok0 + row) * EE + c8;
        *(float4*)dst       = o0;
        *(float4*)(dst + 4) = o1;
    }

    // ---- top-8 + softmax: one lane per token (harness-proven code) ----
    if (t < MT) {
        float tv[TOPK];
        int   ti[TOPK];
#pragma unroll
        for (int q = 0; q < TOPK; ++q) { tv[q] = -INFINITY; ti[q] = 0; }

        for (int e = 0; e < EE; ++e) {
            const float val = slog[t * LS + e];
            if (val > tv[TOPK - 1]) {
                tv[TOPK - 1] = val;
                ti[TOPK - 1] = e;
#pragma unroll
                for (int q = TOPK - 1; q > 0; --q) {
                    if (tv[q] > tv[q - 1]) {   // strict: lowest-index-first on ties
                        float fv = tv[q]; tv[q] = tv[q - 1]; tv[q - 1] = fv;
                        int   fi = ti[q]; ti[q] = ti[q - 1]; ti[q - 1] = fi;
                    }
                }
            }
        }

        const float m = tv[0];
        float ew[TOPK];
        float sum = 0.f;
#pragma unroll
        for (int q = 0; q < TOPK; ++q) { ew[q] = expf(tv[q] - m); sum += ew[q]; }
        const float inv = 1.f / sum;

        const size_t tok = (size_t)(tok0 + t);
        float4 w0, w1, i0, i1;
        w0.x = ew[0] * inv; w0.y = ew[1] * inv; w0.z = ew[2] * inv; w0.w = ew[3] * inv;
        w1.x = ew[4] * inv; w1.y = ew[5] * inv; w1.z = ew[6] * inv; w1.w = ew[7] * inv;
        i0.x = (float)ti[0]; i0.y = (float)ti[1]; i0.z = (float)ti[2]; i0.w = (float)ti[3];
        i1.x = (float)ti[4]; i1.y = (float)ti[5]; i1.z = (float)ti[6]; i1.w = (float)ti[7];
        *(float4*)(out_wts + tok * TOPK)     = w0;
        *(float4*)(out_wts + tok * TOPK + 4) = w1;
        *(float4*)(out_idx + tok * TOPK)     = i0;
        *(float4*)(out_idx + tok * TOPK + 4) = i1;
    }
}

extern "C" void kernel_launch(void* const* d_in, const int* in_sizes, int n_in,
                              void* d_out, int out_size, void* d_ws, size_t ws_size,
                              hipStream_t stream) {
    const float* x = (const float*)d_in[0];   // hidden_states [4,4096,2048] fp32
    const float* w = (const float*)d_in[1];   // gate_w [64,2048] fp32
    float* out        = (float*)d_out;
    float* out_logits = out;                               // 16384*64
    float* out_wts    = out + (size_t)NT * EE;             // 16384*8
    float* out_idx    = out_wts + (size_t)NT * TOPK;       // 16384*8
    short* wsw = (short*)d_ws;                             // 768 KB limb planes

    hipLaunchKernelGGL(wsplit, dim3(EE), dim3(256), 0, stream, w, wsw);
    hipLaunchKernelGGL(router_fused, dim3(NT / MT), dim3(512), 0, stream,
                       x, wsw, out_logits, out_wts, out_idx);
}